// Round 9
// baseline (280.547 us; speedup 1.0000x reference)
//
#include <hip/hip_runtime.h>
#include <math.h>

// clDice loss: 16 x 1 x 1024 x 1024 fp32 inputs, scalar fp32 output.
// Round 9 = Round 8 row-streaming structure with 2 columns per lane
// (float2 pairs): halves/quarters the per-pixel fixed costs (shfl count
// per px drops 4x, load address math per px halves). Dilate computed at
// consumption from e-FIFOs (no hmax FIFOs -> lower VGPR). No LDS, no
// __syncthreads. Edge semantics = value replication (== +/-inf pool pad):
// row edges via wave-uniform substitution selects; column edges (strips
// 0 and 8 only) via per-component dynamic-lane replication shfls.

#define HH 1024
#define WW 1024
#define NIMG 16
constexpr int IMG_ELEMS = HH * WW;
constexpr int VALID = 116;            // output cols per wave (128 - 2*6)
constexpr int NSTRIP = 9;             // 9*116 = 1044 >= 1024
constexpr int NBAND = 12;
constexpr int ROWS_B = 86;            // 12*86 = 1032 >= 1024 (last band 78)
constexpr int NZP = 2 * NIMG;
constexpr int WAVES = NSTRIP * NBAND * NZP;   // 3456
constexpr int BLKT = 256;                      // 4 waves/block
constexpr int NBLK = WAVES / 4;                // 864
constexpr int NGROUP = 24;                     // 96 steps: r0..r0+95
constexpr int PSLOTS = 128;
constexpr int DSLOTS = 16;

// ---- Bowling logistic CDF gelu: gelu(x) = x * sigmoid(1.5976x + 0.0706x^3)
// coefficients pre-multiplied by -log2(e) for raw v_exp_f32 (exp2)
__device__ __forceinline__ float gelu_fast(float x) {
    float u = x * x;
    float w = x * fmaf(u, -0.10180539f, -2.3048494f);
    float e = __builtin_amdgcn_exp2f(w);
    return x * __builtin_amdgcn_rcpf(1.0f + e);
}

__device__ __forceinline__ float sigmoid_fast(float x) {
    float e = __builtin_amdgcn_exp2f(x * -1.442695041f);
    return __builtin_amdgcn_rcpf(1.0f + e);
}

// Column-edge replication: component i takes the value of clamped column
// cc_i, located at lane sl_i component pr_i. Identity for in-image lanes.
__device__ __forceinline__ float2 ce_fix(float2 e, int sl0, int sl1,
                                         bool pr0, bool pr1) {
    float a0 = __shfl(e.x, sl0, 64), b0 = __shfl(e.y, sl0, 64);
    float a1 = __shfl(e.x, sl1, 64), b1 = __shfl(e.y, sl1, 64);
    float2 r;
    r.x = pr0 ? b0 : a0;
    r.y = pr1 ? b1 : a1;
    return r;
}

// One stream step at row r: e1@r-1 .. e4@r-4, skel updates 0..3 at rows
// r-2..r-5. RE = row-edge variant; CE = column-edge strip.
template <bool RE, bool CE>
__device__ __forceinline__ void step_one(
        int u, int r,
        const float* __restrict__ X, const float* __restrict__ OT,
        size_t base, int colc0, int colc1,
        int sl0, int sl1, bool pr0, bool pr1,
        float cmx, float cmy, int rb, int rows, bool PH1,
        float2 (&x)[4], float2 (&e1)[4], float2 (&e2)[4], float2 (&e3)[4],
        float2 (&e4)[4],
        float2 (&sk0)[4], float2 (&sk1)[4], float2 (&sk2)[4], float2 (&oth)[4],
        float2 (&px2)[2], float2 (&pt2)[2],
        float& a0, float& a1, float& d0, float& d1, float& d2) {
    const int I0 = (u + 3) & 3, I1 = (u + 2) & 3, I2 = (u + 1) & 3, I3 = u & 3;
    const int IA = (u + 1) & 1;     // == r & 1 (r0 odd)

    // prefetched X row r; issue load for row r+2
    float2 xv = px2[IA];
    {
        int rc = min(max(r + 2, 0), HH - 1);
        size_t ro = base + (size_t)rc * WW;
        if (CE) { px2[IA].x = X[ro + colc0]; px2[IA].y = X[ro + colc1]; }
        else px2[IA] = *(const float2*)&X[ro + colc0];
    }
    x[I0] = xv;
    // prefetched OT row r-2; issue load for row r
    float2 tv = pt2[IA];
    {
        int rc = min(max(r, 0), HH - 1);
        size_t ro = base + (size_t)rc * WW;
        if (CE) { pt2[IA].x = OT[ro + colc0]; pt2[IA].y = OT[ro + colc1]; }
        else pt2[IA] = *(const float2*)&OT[ro + colc0];
    }

    // ---- e1 @ r-1 (X rows r-2 [I2], r-1 [I1], r [xv]; X row-clamped loads)
    float2 cc = x[I1];
    float lf = __shfl_up(cc.y, 1, 64), rt = __shfl_down(cc.x, 1, 64);
    float2 e1v;
    e1v.x = fminf(fminf(fminf(x[I2].x, xv.x), cc.x), fminf(lf, cc.y));
    e1v.y = fminf(fminf(fminf(x[I2].y, xv.y), cc.y), fminf(cc.x, rt));
    if (CE) e1v = ce_fix(e1v, sl0, sl1, pr0, pr1);
    e1[I1] = e1v;

    // ---- e2 @ r-2 (e1 rows r-3 [I3], r-2 [I2], r-1 [e1v])
    cc = e1[I2];
    float2 up = (RE && r < 3) ? cc : e1[I3];
    float2 dn = (RE && r > 1024) ? cc : e1v;
    lf = __shfl_up(cc.y, 1, 64); rt = __shfl_down(cc.x, 1, 64);
    float2 e2v;
    e2v.x = fminf(fminf(fminf(up.x, dn.x), cc.x), fminf(lf, cc.y));
    e2v.y = fminf(fminf(fminf(up.y, dn.y), cc.y), fminf(cc.x, rt));
    if (CE) e2v = ce_fix(e2v, sl0, sl1, pr0, pr1);
    e2[I2] = e2v;

    // ---- e3 @ r-3 (e2 rows r-4 [I0], r-3 [I3], r-2 [e2v])
    cc = e2[I3];
    up = (RE && r < 4) ? cc : e2[I0];
    dn = (RE && r > 1025) ? cc : e2v;
    lf = __shfl_up(cc.y, 1, 64); rt = __shfl_down(cc.x, 1, 64);
    float2 e3v;
    e3v.x = fminf(fminf(fminf(up.x, dn.x), cc.x), fminf(lf, cc.y));
    e3v.y = fminf(fminf(fminf(up.y, dn.y), cc.y), fminf(cc.x, rt));
    if (CE) e3v = ce_fix(e3v, sl0, sl1, pr0, pr1);
    e3[I3] = e3v;

    // ---- e4 @ r-4 (e3 rows r-5 [I1], r-4 [I0], r-3 [e3v])
    cc = e3[I0];
    up = (RE && r < 5) ? cc : e3[I1];
    dn = (RE && r > 1026) ? cc : e3v;
    lf = __shfl_up(cc.y, 1, 64); rt = __shfl_down(cc.x, 1, 64);
    float2 e4v;
    e4v.x = fminf(fminf(fminf(up.x, dn.x), cc.x), fminf(lf, cc.y));
    e4v.y = fminf(fminf(fminf(up.y, dn.y), cc.y), fminf(cc.x, rt));
    if (CE) e4v = ce_fix(e4v, sl0, sl1, pr0, pr1);
    e4[I0] = e4v;

    // ---- update0 @ r-2: dil(e1 rows r-3 [I3], r-2 [I2], r-1 [e1v])
    {
        float2 ctr = e1[I2];
        float2 wu = (RE && r < 3) ? ctr : e1[I3];
        float2 wd = (RE && r > 1024) ? ctr : e1v;
        float2 vm;
        vm.x = fmaxf(fmaxf(wu.x, ctr.x), wd.x);
        vm.y = fmaxf(fmaxf(wu.y, ctr.y), wd.y);
        float lv = __shfl_up(vm.y, 1, 64), rv = __shfl_down(vm.x, 1, 64);
        float2 p0 = x[I2];
        float2 s;
        s.x = gelu_fast(p0.x - fmaxf(fmaxf(lv, vm.x), vm.y));
        s.y = gelu_fast(p0.y - fmaxf(fmaxf(vm.x, vm.y), rv));
        sk0[I2] = s;
        oth[I2] = tv;
        if (PH1 && (unsigned)(r - 2 - rb) < (unsigned)rows) {
            float pvx = sigmoid_fast(p0.x) * cmx;
            float pvy = sigmoid_fast(p0.y) * cmy;
            d0 = fmaf(pvx, tv.x, fmaf(pvy, tv.y, d0));
            d1 += pvx + pvy;
            d2 = fmaf(tv.x, cmx, fmaf(tv.y, cmy, d2));
        }
    }

    // ---- update1 @ r-3: dil(e2 rows r-4 [I0], r-3 [I3], r-2 [e2v])
    {
        float2 ctr = e2[I3];
        float2 wu = (RE && r < 4) ? ctr : e2[I0];
        float2 wd = (RE && r > 1025) ? ctr : e2v;
        float2 vm;
        vm.x = fmaxf(fmaxf(wu.x, ctr.x), wd.x);
        vm.y = fmaxf(fmaxf(wu.y, ctr.y), wd.y);
        float lv = __shfl_up(vm.y, 1, 64), rv = __shfl_down(vm.x, 1, 64);
        float2 dlt;
        dlt.x = gelu_fast(e1[I3].x - fmaxf(fmaxf(lv, vm.x), vm.y));
        dlt.y = gelu_fast(e1[I3].y - fmaxf(fmaxf(vm.x, vm.y), rv));
        float2 s0v = sk0[I3];
        sk1[I3].x = s0v.x + gelu_fast(fmaf(-s0v.x, dlt.x, dlt.x));
        sk1[I3].y = s0v.y + gelu_fast(fmaf(-s0v.y, dlt.y, dlt.y));
    }

    // ---- update2 @ r-4: dil(e3 rows r-5 [I1], r-4 [I0], r-3 [e3v])
    {
        float2 ctr = e3[I0];
        float2 wu = (RE && r < 5) ? ctr : e3[I1];
        float2 wd = (RE && r > 1026) ? ctr : e3v;
        float2 vm;
        vm.x = fmaxf(fmaxf(wu.x, ctr.x), wd.x);
        vm.y = fmaxf(fmaxf(wu.y, ctr.y), wd.y);
        float lv = __shfl_up(vm.y, 1, 64), rv = __shfl_down(vm.x, 1, 64);
        float2 dlt;
        dlt.x = gelu_fast(e2[I0].x - fmaxf(fmaxf(lv, vm.x), vm.y));
        dlt.y = gelu_fast(e2[I0].y - fmaxf(fmaxf(vm.x, vm.y), rv));
        float2 s1v = sk1[I0];
        sk2[I0].x = s1v.x + gelu_fast(fmaf(-s1v.x, dlt.x, dlt.x));
        sk2[I0].y = s1v.y + gelu_fast(fmaf(-s1v.y, dlt.y, dlt.y));
    }

    // ---- update3 @ r-5: dil(e4 rows r-6 [I2], r-5 [I1], r-4 [e4v])
    {
        float2 ctr = e4[I1];
        float2 wu = (RE && r < 6) ? ctr : e4[I2];
        float2 wd = (RE && r > 1027) ? ctr : e4v;
        float2 vm;
        vm.x = fmaxf(fmaxf(wu.x, ctr.x), wd.x);
        vm.y = fmaxf(fmaxf(wu.y, ctr.y), wd.y);
        float lv = __shfl_up(vm.y, 1, 64), rv = __shfl_down(vm.x, 1, 64);
        float2 dlt;
        dlt.x = gelu_fast(e3[I1].x - fmaxf(fmaxf(lv, vm.x), vm.y));
        dlt.y = gelu_fast(e3[I1].y - fmaxf(fmaxf(vm.x, vm.y), rv));
        float2 s2v = sk2[I1];
        float sx = s2v.x + gelu_fast(fmaf(-s2v.x, dlt.x, dlt.x));
        float sy = s2v.y + gelu_fast(fmaf(-s2v.y, dlt.y, dlt.y));
        if ((unsigned)(r - 5 - rb) < (unsigned)rows) {
            float mx = sx * cmx, my = sy * cmy;
            float2 o5 = oth[I1];
            a0 += mx + my;
            a1 = fmaf(mx, o5.x, fmaf(my, o5.y, a1));
        }
    }
}

template <bool CE>
__device__ __forceinline__ void run_band(
        const float* __restrict__ X, const float* __restrict__ OT,
        size_t base, int colc0, int colc1, int sl0, int sl1, bool pr0, bool pr1,
        float cmx, float cmy, int rb, int rows, bool PH1,
        float& a0, float& a1, float& d0, float& d1, float& d2) {
    float2 z; z.x = 0.f; z.y = 0.f;
    float2 x[4] = {z, z, z, z}, e1[4] = {z, z, z, z}, e2[4] = {z, z, z, z},
           e3[4] = {z, z, z, z}, e4[4] = {z, z, z, z},
           sk0[4] = {z, z, z, z}, sk1[4] = {z, z, z, z}, sk2[4] = {z, z, z, z},
           oth[4] = {z, z, z, z};
    float2 px2[2], pt2[2];

    const int r0 = rb - 5;   // rb even -> r0 odd (IA == r & 1 holds)
    {
        auto ld = [&](const float* __restrict__ P, int rr) -> float2 {
            int rc = min(max(rr, 0), HH - 1);
            size_t ro = base + (size_t)rc * WW;
            float2 v;
            if (CE) { v.x = P[ro + colc0]; v.y = P[ro + colc1]; }
            else v = *(const float2*)&P[ro + colc0];
            return v;
        };
        px2[r0 & 1] = ld(X, r0);
        px2[(r0 + 1) & 1] = ld(X, r0 + 1);
        pt2[r0 & 1] = ld(OT, r0 - 2);
        pt2[(r0 + 1) & 1] = ld(OT, r0 - 1);
    }

    for (int g = 0; g < NGROUP; g++) {
        const int rg = r0 + g * 4;
        if (rg < 6 || rg > 1021) {
#pragma unroll
            for (int u = 0; u < 4; u++)
                step_one<true, CE>(u, rg + u, X, OT, base, colc0, colc1,
                                   sl0, sl1, pr0, pr1, cmx, cmy, rb, rows, PH1,
                                   x, e1, e2, e3, e4, sk0, sk1, sk2, oth,
                                   px2, pt2, a0, a1, d0, d1, d2);
        } else {
#pragma unroll
            for (int u = 0; u < 4; u++)
                step_one<false, CE>(u, rg + u, X, OT, base, colc0, colc1,
                                    sl0, sl1, pr0, pr1, cmx, cmy, rb, rows, PH1,
                                    x, e1, e2, e3, e4, sk0, sk1, sk2, oth,
                                    px2, pt2, a0, a1, d0, d1, d2);
        }
    }
}

// accP: PSLOTS cachelines of 32 floats: slot*32 + {0:sumP,1:sumP*t,2:sumT,3:sumT*p}
// accD: (img*DSLOTS + s)*32 + {0:inter, 1:sum sigmoid(p), 2:sum t}
__global__ __launch_bounds__(BLKT, 4) void cl_stream(
        const float* __restrict__ y_pred,
        const float* __restrict__ y_true,
        float* __restrict__ accP,
        float* __restrict__ accD) {
    const int wv = blockIdx.x * 4 + (threadIdx.x >> 6);
    const int lane = threadIdx.x & 63;
    int tmp = wv;
    const int strip = tmp % NSTRIP; tmp /= NSTRIP;
    const int band = tmp % NBAND;   tmp /= NBAND;
    const int img = tmp & (NIMG - 1);
    const bool PH1 = tmp < NIMG;
    const float* __restrict__ X  = PH1 ? y_pred : y_true;
    const float* __restrict__ OT = PH1 ? y_true : y_pred;
    const size_t base = (size_t)img * IMG_ELEMS;

    // column-pair geometry: even base -> aligned float2 loads
    const int sbase = strip * VALID - 6;
    const int c0 = sbase + 2 * lane, c1 = c0 + 1;
    const int cc0 = min(max(c0, 0), WW - 1), cc1 = min(max(c1, 0), WW - 1);
    const int dd0 = cc0 - sbase, dd1 = cc1 - sbase;
    const int sl0 = dd0 >> 1, sl1 = dd1 >> 1;
    const bool pr0 = (dd0 & 1) != 0, pr1 = (dd1 & 1) != 0;
    const bool colEdge = (strip == 0) || (strip == NSTRIP - 1);
    const float cmx = (lane >= 3 && lane <= 60 && c0 < WW) ? 1.0f : 0.0f;
    const float cmy = (lane >= 3 && lane <= 60 && c1 < WW) ? 1.0f : 0.0f;
    const int rb = band * ROWS_B;
    const int rows = min(ROWS_B, HH - rb);

    float a0 = 0.f, a1 = 0.f, d0 = 0.f, d1 = 0.f, d2 = 0.f;
    if (colEdge)
        run_band<true >(X, OT, base, cc0, cc1, sl0, sl1, pr0, pr1,
                        cmx, cmy, rb, rows, PH1, a0, a1, d0, d1, d2);
    else
        run_band<false>(X, OT, base, cc0, cc1, sl0, sl1, pr0, pr1,
                        cmx, cmy, rb, rows, PH1, a0, a1, d0, d1, d2);

    // ---- wave reduce + spread atomics
    for (int o = 1; o < 64; o <<= 1) {
        a0 += __shfl_xor(a0, o, 64);
        a1 += __shfl_xor(a1, o, 64);
    }
    if (PH1) {
        for (int o = 1; o < 64; o <<= 1) {
            d0 += __shfl_xor(d0, o, 64);
            d1 += __shfl_xor(d1, o, 64);
            d2 += __shfl_xor(d2, o, 64);
        }
    }
    if (lane == 0) {
        int slot = (wv * 37) & (PSLOTS - 1);
        atomicAdd(&accP[slot * 32 + (PH1 ? 0 : 2)], a0);
        atomicAdd(&accP[slot * 32 + (PH1 ? 1 : 3)], a1);
        if (PH1) {
            int ds = (strip + band * 7) & (DSLOTS - 1);
            float* dst = accD + (size_t)(img * DSLOTS + ds) * 32;
            atomicAdd(&dst[0], d0);
            atomicAdd(&dst[1], d1);
            atomicAdd(&dst[2], d2);
        }
    }
}

__global__ __launch_bounds__(256) void final_combine(
        const float* __restrict__ accP,
        const float* __restrict__ accD,
        float* __restrict__ out) {
    __shared__ float shp[2][4];
    __shared__ float shd[NIMG][3];
    int tid = threadIdx.x;
    int lane = tid & 63, wave = tid >> 6;

    float p0 = 0.f, p1 = 0.f, p2 = 0.f, p3 = 0.f;
    if (tid < PSLOTS) {
        const float* s = accP + tid * 32;
        p0 = s[0]; p1 = s[1]; p2 = s[2]; p3 = s[3];
    }
    for (int o = 32; o > 0; o >>= 1) {
        p0 += __shfl_down(p0, o, 64); p1 += __shfl_down(p1, o, 64);
        p2 += __shfl_down(p2, o, 64); p3 += __shfl_down(p3, o, 64);
    }
    if (lane == 0 && wave < 2) {
        shp[wave][0] = p0; shp[wave][1] = p1; shp[wave][2] = p2; shp[wave][3] = p3;
    }

    int n = tid >> 4, s16 = tid & 15;
    const float* d = accD + (size_t)(n * DSLOTS + s16) * 32;
    float q0 = d[0], q1 = d[1], q2 = d[2];
    for (int o = 8; o > 0; o >>= 1) {
        q0 += __shfl_down(q0, o, 16);
        q1 += __shfl_down(q1, o, 16);
        q2 += __shfl_down(q2, o, 16);
    }
    if (s16 == 0) { shd[n][0] = q0; shd[n][1] = q1; shd[n][2] = q2; }
    __syncthreads();

    if (tid == 0) {
        float sumP  = shp[0][0] + shp[1][0];
        float sumPt = shp[0][1] + shp[1][1];
        float sumT  = shp[0][2] + shp[1][2];
        float sumTp = shp[0][3] + shp[1][3];
        const float SMOOTH = 1.0f;
        float tprec = (sumPt + SMOOTH) / (sumP + SMOOTH);
        float tsens = (sumTp + SMOOTH) / (sumT + SMOOTH);
        float cl = 1.0f - 2.0f * (tprec * tsens) / (tprec + tsens);
        const float EPS = 1e-4f;
        float dsum = 0.f;
        for (int k = 0; k < NIMG; k++) {
            float gd = (2.0f * shd[k][0] + EPS) / (shd[k][1] + shd[k][2] + EPS);
            dsum += 1.0f - gd;
        }
        out[0] = 0.5f * cl + 0.5f * (dsum / (float)NIMG);
    }
}

extern "C" void kernel_launch(void* const* d_in, const int* in_sizes, int n_in,
                              void* d_out, int out_size, void* d_ws, size_t ws_size,
                              hipStream_t stream) {
    const float* y_pred = (const float*)d_in[0];
    const float* y_true = (const float*)d_in[1];
    float* out = (float*)d_out;

    float* accP = (float*)d_ws;                  // 128*32 floats
    float* accD = accP + PSLOTS * 32;            // 16*16*32 floats

    hipMemsetAsync(accP, 0, (PSLOTS * 32 + NIMG * DSLOTS * 32) * sizeof(float),
                   stream);

    cl_stream<<<NBLK, BLKT, 0, stream>>>(y_pred, y_true, accP, accD);
    final_combine<<<1, 256, 0, stream>>>(accP, accD, out);
}

// Round 10
// 252.246 us; speedup vs baseline: 1.1122x; 1.1122x over previous
//
#include <hip/hip_runtime.h>
#include <math.h>

// clDice loss: 16 x 1 x 1024 x 1024 fp32 inputs, scalar fp32 output.
// Round 10 = Round 9 (2 columns/lane float2 row streaming, no LDS, no
// barriers) with the spill fixed: no min-waves launch bound (allocator
// free to use ~120 VGPRs; still 4 waves/SIMD) and band count tuned so
// waves/SIMD ~= 3.94 (98% wave-slot utilization).

#define HH 1024
#define WW 1024
#define NIMG 16
constexpr int IMG_ELEMS = HH * WW;
constexpr int VALID = 116;            // output cols per wave (128 - 2*6)
constexpr int NSTRIP = 9;             // 9*116 = 1044 >= 1024
constexpr int NBAND = 14;
constexpr int ROWS_B = 74;            // 14*74 = 1036 >= 1024 (last band 62)
constexpr int NZP = 2 * NIMG;
constexpr int WAVES = NSTRIP * NBAND * NZP;   // 4032 -> 3.94/SIMD
constexpr int BLKT = 256;                      // 4 waves/block
constexpr int NBLK = WAVES / 4;                // 1008
constexpr int NGROUP = 21;                     // 84 steps: r0..r0+83
constexpr int PSLOTS = 128;
constexpr int DSLOTS = 16;

// ---- Bowling logistic CDF gelu: gelu(x) = x * sigmoid(1.5976x + 0.0706x^3)
// coefficients pre-multiplied by -log2(e) for raw v_exp_f32 (exp2)
__device__ __forceinline__ float gelu_fast(float x) {
    float u = x * x;
    float w = x * fmaf(u, -0.10180539f, -2.3048494f);
    float e = __builtin_amdgcn_exp2f(w);
    return x * __builtin_amdgcn_rcpf(1.0f + e);
}

__device__ __forceinline__ float sigmoid_fast(float x) {
    float e = __builtin_amdgcn_exp2f(x * -1.442695041f);
    return __builtin_amdgcn_rcpf(1.0f + e);
}

// Column-edge replication: component i takes the value of clamped column
// cc_i, located at lane sl_i component pr_i. Identity for in-image lanes.
__device__ __forceinline__ float2 ce_fix(float2 e, int sl0, int sl1,
                                         bool pr0, bool pr1) {
    float a0 = __shfl(e.x, sl0, 64), b0 = __shfl(e.y, sl0, 64);
    float a1 = __shfl(e.x, sl1, 64), b1 = __shfl(e.y, sl1, 64);
    float2 r;
    r.x = pr0 ? b0 : a0;
    r.y = pr1 ? b1 : a1;
    return r;
}

// One stream step at row r: e1@r-1 .. e4@r-4, skel updates 0..3 at rows
// r-2..r-5. RE = row-edge variant; CE = column-edge strip.
template <bool RE, bool CE>
__device__ __forceinline__ void step_one(
        int u, int r,
        const float* __restrict__ X, const float* __restrict__ OT,
        size_t base, int colc0, int colc1,
        int sl0, int sl1, bool pr0, bool pr1,
        float cmx, float cmy, int rb, int rows, bool PH1,
        float2 (&x)[4], float2 (&e1)[4], float2 (&e2)[4], float2 (&e3)[4],
        float2 (&e4)[4],
        float2 (&sk0)[4], float2 (&sk1)[4], float2 (&sk2)[4], float2 (&oth)[4],
        float2 (&px2)[2], float2 (&pt2)[2],
        float& a0, float& a1, float& d0, float& d1, float& d2) {
    const int I0 = (u + 3) & 3, I1 = (u + 2) & 3, I2 = (u + 1) & 3, I3 = u & 3;
    const int IA = (u + 1) & 1;     // == r & 1 (r0 odd)

    // prefetched X row r; issue load for row r+2
    float2 xv = px2[IA];
    {
        int rc = min(max(r + 2, 0), HH - 1);
        size_t ro = base + (size_t)rc * WW;
        if (CE) { px2[IA].x = X[ro + colc0]; px2[IA].y = X[ro + colc1]; }
        else px2[IA] = *(const float2*)&X[ro + colc0];
    }
    x[I0] = xv;
    // prefetched OT row r-2; issue load for row r
    float2 tv = pt2[IA];
    {
        int rc = min(max(r, 0), HH - 1);
        size_t ro = base + (size_t)rc * WW;
        if (CE) { pt2[IA].x = OT[ro + colc0]; pt2[IA].y = OT[ro + colc1]; }
        else pt2[IA] = *(const float2*)&OT[ro + colc0];
    }

    // ---- e1 @ r-1 (X rows r-2 [I2], r-1 [I1], r [xv]; X row-clamped loads)
    float2 cc = x[I1];
    float lf = __shfl_up(cc.y, 1, 64), rt = __shfl_down(cc.x, 1, 64);
    float2 e1v;
    e1v.x = fminf(fminf(fminf(x[I2].x, xv.x), cc.x), fminf(lf, cc.y));
    e1v.y = fminf(fminf(fminf(x[I2].y, xv.y), cc.y), fminf(cc.x, rt));
    if (CE) e1v = ce_fix(e1v, sl0, sl1, pr0, pr1);
    e1[I1] = e1v;

    // ---- e2 @ r-2 (e1 rows r-3 [I3], r-2 [I2], r-1 [e1v])
    cc = e1[I2];
    float2 up = (RE && r < 3) ? cc : e1[I3];
    float2 dn = (RE && r > 1024) ? cc : e1v;
    lf = __shfl_up(cc.y, 1, 64); rt = __shfl_down(cc.x, 1, 64);
    float2 e2v;
    e2v.x = fminf(fminf(fminf(up.x, dn.x), cc.x), fminf(lf, cc.y));
    e2v.y = fminf(fminf(fminf(up.y, dn.y), cc.y), fminf(cc.x, rt));
    if (CE) e2v = ce_fix(e2v, sl0, sl1, pr0, pr1);
    e2[I2] = e2v;

    // ---- e3 @ r-3 (e2 rows r-4 [I0], r-3 [I3], r-2 [e2v])
    cc = e2[I3];
    up = (RE && r < 4) ? cc : e2[I0];
    dn = (RE && r > 1025) ? cc : e2v;
    lf = __shfl_up(cc.y, 1, 64); rt = __shfl_down(cc.x, 1, 64);
    float2 e3v;
    e3v.x = fminf(fminf(fminf(up.x, dn.x), cc.x), fminf(lf, cc.y));
    e3v.y = fminf(fminf(fminf(up.y, dn.y), cc.y), fminf(cc.x, rt));
    if (CE) e3v = ce_fix(e3v, sl0, sl1, pr0, pr1);
    e3[I3] = e3v;

    // ---- e4 @ r-4 (e3 rows r-5 [I1], r-4 [I0], r-3 [e3v])
    cc = e3[I0];
    up = (RE && r < 5) ? cc : e3[I1];
    dn = (RE && r > 1026) ? cc : e3v;
    lf = __shfl_up(cc.y, 1, 64); rt = __shfl_down(cc.x, 1, 64);
    float2 e4v;
    e4v.x = fminf(fminf(fminf(up.x, dn.x), cc.x), fminf(lf, cc.y));
    e4v.y = fminf(fminf(fminf(up.y, dn.y), cc.y), fminf(cc.x, rt));
    if (CE) e4v = ce_fix(e4v, sl0, sl1, pr0, pr1);
    e4[I0] = e4v;

    // ---- update0 @ r-2: dil(e1 rows r-3 [I3], r-2 [I2], r-1 [e1v])
    {
        float2 ctr = e1[I2];
        float2 wu = (RE && r < 3) ? ctr : e1[I3];
        float2 wd = (RE && r > 1024) ? ctr : e1v;
        float2 vm;
        vm.x = fmaxf(fmaxf(wu.x, ctr.x), wd.x);
        vm.y = fmaxf(fmaxf(wu.y, ctr.y), wd.y);
        float lv = __shfl_up(vm.y, 1, 64), rv = __shfl_down(vm.x, 1, 64);
        float2 p0 = x[I2];
        float2 s;
        s.x = gelu_fast(p0.x - fmaxf(fmaxf(lv, vm.x), vm.y));
        s.y = gelu_fast(p0.y - fmaxf(fmaxf(vm.x, vm.y), rv));
        sk0[I2] = s;
        oth[I2] = tv;
        if (PH1 && (unsigned)(r - 2 - rb) < (unsigned)rows) {
            float pvx = sigmoid_fast(p0.x) * cmx;
            float pvy = sigmoid_fast(p0.y) * cmy;
            d0 = fmaf(pvx, tv.x, fmaf(pvy, tv.y, d0));
            d1 += pvx + pvy;
            d2 = fmaf(tv.x, cmx, fmaf(tv.y, cmy, d2));
        }
    }

    // ---- update1 @ r-3: dil(e2 rows r-4 [I0], r-3 [I3], r-2 [e2v])
    {
        float2 ctr = e2[I3];
        float2 wu = (RE && r < 4) ? ctr : e2[I0];
        float2 wd = (RE && r > 1025) ? ctr : e2v;
        float2 vm;
        vm.x = fmaxf(fmaxf(wu.x, ctr.x), wd.x);
        vm.y = fmaxf(fmaxf(wu.y, ctr.y), wd.y);
        float lv = __shfl_up(vm.y, 1, 64), rv = __shfl_down(vm.x, 1, 64);
        float2 dlt;
        dlt.x = gelu_fast(e1[I3].x - fmaxf(fmaxf(lv, vm.x), vm.y));
        dlt.y = gelu_fast(e1[I3].y - fmaxf(fmaxf(vm.x, vm.y), rv));
        float2 s0v = sk0[I3];
        sk1[I3].x = s0v.x + gelu_fast(fmaf(-s0v.x, dlt.x, dlt.x));
        sk1[I3].y = s0v.y + gelu_fast(fmaf(-s0v.y, dlt.y, dlt.y));
    }

    // ---- update2 @ r-4: dil(e3 rows r-5 [I1], r-4 [I0], r-3 [e3v])
    {
        float2 ctr = e3[I0];
        float2 wu = (RE && r < 5) ? ctr : e3[I1];
        float2 wd = (RE && r > 1026) ? ctr : e3v;
        float2 vm;
        vm.x = fmaxf(fmaxf(wu.x, ctr.x), wd.x);
        vm.y = fmaxf(fmaxf(wu.y, ctr.y), wd.y);
        float lv = __shfl_up(vm.y, 1, 64), rv = __shfl_down(vm.x, 1, 64);
        float2 dlt;
        dlt.x = gelu_fast(e2[I0].x - fmaxf(fmaxf(lv, vm.x), vm.y));
        dlt.y = gelu_fast(e2[I0].y - fmaxf(fmaxf(vm.x, vm.y), rv));
        float2 s1v = sk1[I0];
        sk2[I0].x = s1v.x + gelu_fast(fmaf(-s1v.x, dlt.x, dlt.x));
        sk2[I0].y = s1v.y + gelu_fast(fmaf(-s1v.y, dlt.y, dlt.y));
    }

    // ---- update3 @ r-5: dil(e4 rows r-6 [I2], r-5 [I1], r-4 [e4v])
    {
        float2 ctr = e4[I1];
        float2 wu = (RE && r < 6) ? ctr : e4[I2];
        float2 wd = (RE && r > 1027) ? ctr : e4v;
        float2 vm;
        vm.x = fmaxf(fmaxf(wu.x, ctr.x), wd.x);
        vm.y = fmaxf(fmaxf(wu.y, ctr.y), wd.y);
        float lv = __shfl_up(vm.y, 1, 64), rv = __shfl_down(vm.x, 1, 64);
        float2 dlt;
        dlt.x = gelu_fast(e3[I1].x - fmaxf(fmaxf(lv, vm.x), vm.y));
        dlt.y = gelu_fast(e3[I1].y - fmaxf(fmaxf(vm.x, vm.y), rv));
        float2 s2v = sk2[I1];
        float sx = s2v.x + gelu_fast(fmaf(-s2v.x, dlt.x, dlt.x));
        float sy = s2v.y + gelu_fast(fmaf(-s2v.y, dlt.y, dlt.y));
        if ((unsigned)(r - 5 - rb) < (unsigned)rows) {
            float mx = sx * cmx, my = sy * cmy;
            float2 o5 = oth[I1];
            a0 += mx + my;
            a1 = fmaf(mx, o5.x, fmaf(my, o5.y, a1));
        }
    }
}

template <bool CE>
__device__ __forceinline__ void run_band(
        const float* __restrict__ X, const float* __restrict__ OT,
        size_t base, int colc0, int colc1, int sl0, int sl1, bool pr0, bool pr1,
        float cmx, float cmy, int rb, int rows, bool PH1,
        float& a0, float& a1, float& d0, float& d1, float& d2) {
    float2 z; z.x = 0.f; z.y = 0.f;
    float2 x[4] = {z, z, z, z}, e1[4] = {z, z, z, z}, e2[4] = {z, z, z, z},
           e3[4] = {z, z, z, z}, e4[4] = {z, z, z, z},
           sk0[4] = {z, z, z, z}, sk1[4] = {z, z, z, z}, sk2[4] = {z, z, z, z},
           oth[4] = {z, z, z, z};
    float2 px2[2], pt2[2];

    const int r0 = rb - 5;   // rb even -> r0 odd (IA == r & 1 holds)
    {
        auto ld = [&](const float* __restrict__ P, int rr) -> float2 {
            int rc = min(max(rr, 0), HH - 1);
            size_t ro = base + (size_t)rc * WW;
            float2 v;
            if (CE) { v.x = P[ro + colc0]; v.y = P[ro + colc1]; }
            else v = *(const float2*)&P[ro + colc0];
            return v;
        };
        px2[r0 & 1] = ld(X, r0);
        px2[(r0 + 1) & 1] = ld(X, r0 + 1);
        pt2[r0 & 1] = ld(OT, r0 - 2);
        pt2[(r0 + 1) & 1] = ld(OT, r0 - 1);
    }

    for (int g = 0; g < NGROUP; g++) {
        const int rg = r0 + g * 4;
        if (rg < 6 || rg > 1021) {
#pragma unroll
            for (int u = 0; u < 4; u++)
                step_one<true, CE>(u, rg + u, X, OT, base, colc0, colc1,
                                   sl0, sl1, pr0, pr1, cmx, cmy, rb, rows, PH1,
                                   x, e1, e2, e3, e4, sk0, sk1, sk2, oth,
                                   px2, pt2, a0, a1, d0, d1, d2);
        } else {
#pragma unroll
            for (int u = 0; u < 4; u++)
                step_one<false, CE>(u, rg + u, X, OT, base, colc0, colc1,
                                    sl0, sl1, pr0, pr1, cmx, cmy, rb, rows, PH1,
                                    x, e1, e2, e3, e4, sk0, sk1, sk2, oth,
                                    px2, pt2, a0, a1, d0, d1, d2);
        }
    }
}

// accP: PSLOTS cachelines of 32 floats: slot*32 + {0:sumP,1:sumP*t,2:sumT,3:sumT*p}
// accD: (img*DSLOTS + s)*32 + {0:inter, 1:sum sigmoid(p), 2:sum t}
__global__ __launch_bounds__(BLKT) void cl_stream(
        const float* __restrict__ y_pred,
        const float* __restrict__ y_true,
        float* __restrict__ accP,
        float* __restrict__ accD) {
    const int wv = blockIdx.x * 4 + (threadIdx.x >> 6);
    const int lane = threadIdx.x & 63;
    int tmp = wv;
    const int strip = tmp % NSTRIP; tmp /= NSTRIP;
    const int band = tmp % NBAND;   tmp /= NBAND;
    const int img = tmp & (NIMG - 1);
    const bool PH1 = tmp < NIMG;
    const float* __restrict__ X  = PH1 ? y_pred : y_true;
    const float* __restrict__ OT = PH1 ? y_true : y_pred;
    const size_t base = (size_t)img * IMG_ELEMS;

    // column-pair geometry: even base -> aligned float2 loads
    const int sbase = strip * VALID - 6;
    const int c0 = sbase + 2 * lane, c1 = c0 + 1;
    const int cc0 = min(max(c0, 0), WW - 1), cc1 = min(max(c1, 0), WW - 1);
    const int dd0 = cc0 - sbase, dd1 = cc1 - sbase;
    const int sl0 = dd0 >> 1, sl1 = dd1 >> 1;
    const bool pr0 = (dd0 & 1) != 0, pr1 = (dd1 & 1) != 0;
    const bool colEdge = (strip == 0) || (strip == NSTRIP - 1);
    const float cmx = (lane >= 3 && lane <= 60 && c0 < WW) ? 1.0f : 0.0f;
    const float cmy = (lane >= 3 && lane <= 60 && c1 < WW) ? 1.0f : 0.0f;
    const int rb = band * ROWS_B;
    const int rows = min(ROWS_B, HH - rb);

    float a0 = 0.f, a1 = 0.f, d0 = 0.f, d1 = 0.f, d2 = 0.f;
    if (colEdge)
        run_band<true >(X, OT, base, cc0, cc1, sl0, sl1, pr0, pr1,
                        cmx, cmy, rb, rows, PH1, a0, a1, d0, d1, d2);
    else
        run_band<false>(X, OT, base, cc0, cc1, sl0, sl1, pr0, pr1,
                        cmx, cmy, rb, rows, PH1, a0, a1, d0, d1, d2);

    // ---- wave reduce + spread atomics
    for (int o = 1; o < 64; o <<= 1) {
        a0 += __shfl_xor(a0, o, 64);
        a1 += __shfl_xor(a1, o, 64);
    }
    if (PH1) {
        for (int o = 1; o < 64; o <<= 1) {
            d0 += __shfl_xor(d0, o, 64);
            d1 += __shfl_xor(d1, o, 64);
            d2 += __shfl_xor(d2, o, 64);
        }
    }
    if (lane == 0) {
        int slot = (wv * 37) & (PSLOTS - 1);
        atomicAdd(&accP[slot * 32 + (PH1 ? 0 : 2)], a0);
        atomicAdd(&accP[slot * 32 + (PH1 ? 1 : 3)], a1);
        if (PH1) {
            int ds = (strip + band * 7) & (DSLOTS - 1);
            float* dst = accD + (size_t)(img * DSLOTS + ds) * 32;
            atomicAdd(&dst[0], d0);
            atomicAdd(&dst[1], d1);
            atomicAdd(&dst[2], d2);
        }
    }
}

__global__ __launch_bounds__(256) void final_combine(
        const float* __restrict__ accP,
        const float* __restrict__ accD,
        float* __restrict__ out) {
    __shared__ float shp[2][4];
    __shared__ float shd[NIMG][3];
    int tid = threadIdx.x;
    int lane = tid & 63, wave = tid >> 6;

    float p0 = 0.f, p1 = 0.f, p2 = 0.f, p3 = 0.f;
    if (tid < PSLOTS) {
        const float* s = accP + tid * 32;
        p0 = s[0]; p1 = s[1]; p2 = s[2]; p3 = s[3];
    }
    for (int o = 32; o > 0; o >>= 1) {
        p0 += __shfl_down(p0, o, 64); p1 += __shfl_down(p1, o, 64);
        p2 += __shfl_down(p2, o, 64); p3 += __shfl_down(p3, o, 64);
    }
    if (lane == 0 && wave < 2) {
        shp[wave][0] = p0; shp[wave][1] = p1; shp[wave][2] = p2; shp[wave][3] = p3;
    }

    int n = tid >> 4, s16 = tid & 15;
    const float* d = accD + (size_t)(n * DSLOTS + s16) * 32;
    float q0 = d[0], q1 = d[1], q2 = d[2];
    for (int o = 8; o > 0; o >>= 1) {
        q0 += __shfl_down(q0, o, 16);
        q1 += __shfl_down(q1, o, 16);
        q2 += __shfl_down(q2, o, 16);
    }
    if (s16 == 0) { shd[n][0] = q0; shd[n][1] = q1; shd[n][2] = q2; }
    __syncthreads();

    if (tid == 0) {
        float sumP  = shp[0][0] + shp[1][0];
        float sumPt = shp[0][1] + shp[1][1];
        float sumT  = shp[0][2] + shp[1][2];
        float sumTp = shp[0][3] + shp[1][3];
        const float SMOOTH = 1.0f;
        float tprec = (sumPt + SMOOTH) / (sumP + SMOOTH);
        float tsens = (sumTp + SMOOTH) / (sumT + SMOOTH);
        float cl = 1.0f - 2.0f * (tprec * tsens) / (tprec + tsens);
        const float EPS = 1e-4f;
        float dsum = 0.f;
        for (int k = 0; k < NIMG; k++) {
            float gd = (2.0f * shd[k][0] + EPS) / (shd[k][1] + shd[k][2] + EPS);
            dsum += 1.0f - gd;
        }
        out[0] = 0.5f * cl + 0.5f * (dsum / (float)NIMG);
    }
}

extern "C" void kernel_launch(void* const* d_in, const int* in_sizes, int n_in,
                              void* d_out, int out_size, void* d_ws, size_t ws_size,
                              hipStream_t stream) {
    const float* y_pred = (const float*)d_in[0];
    const float* y_true = (const float*)d_in[1];
    float* out = (float*)d_out;

    float* accP = (float*)d_ws;                  // 128*32 floats
    float* accD = accP + PSLOTS * 32;            // 16*16*32 floats

    hipMemsetAsync(accP, 0, (PSLOTS * 32 + NIMG * DSLOTS * 32) * sizeof(float),
                   stream);

    cl_stream<<<NBLK, BLKT, 0, stream>>>(y_pred, y_true, accP, accD);
    final_combine<<<1, 256, 0, stream>>>(accP, accD, out);
}